// Round 1
// 292.339 us; speedup vs baseline: 1.0351x; 1.0351x over previous
//
#include <hip/hip_runtime.h>
#include <math.h>

#define NEMB 256
#define DIM 64
#define SIGS 128
#define THREADS 512
#define NSIG 131072
#define GRID (NSIG / SIGS)

#define LOG1P50 3.9318256327243257        // np.log1p(50.0), f64
#define INV_MU_F ((float)(1.0 / LOG1P50)) // fp32-rounded scalar, as numpy uses
#define TWO15_F ((float)(2.0 / 15.0))

// dynamic LDS layout (byte offsets) — Dn NOT staged (L2-hot from global)
#define LB_SIG   0          // 32768 B : sig f32 [c][w]
#define LB_XS    32768      // 2048 B  : raw coeffs f32 [4][SIGS] (quantized in-place)
#define LB_QI    34816      // 2048 B  : qi i32 [4][SIGS]
#define LB_RED   36864      // 64 B    : per-wave loss partials (f64)
#define LDS_BYTES 36928

typedef float f2 __attribute__((ext_vector_type(2)));

__device__ __forceinline__ float rdlane_f(float v, int lane)
{
    return __builtin_bit_cast(float, __builtin_amdgcn_readlane(__builtin_bit_cast(int, v), lane));
}

template<int CTRL>
__device__ __forceinline__ float dpp_fmax(float m)
{
    int sh = __builtin_amdgcn_update_dpp(0, __builtin_bit_cast(int, m), CTRL, 0xf, 0xf, true);
    return fmaxf(m, __builtin_bit_cast(float, sh));
}

// wave-wide max of non-negative values; valid in lane 63. Pure VALU (DPP),
// replaces the 6-deep ds_swizzle shfl_xor chain (LDS-pipe, ~200cy).
__device__ __forceinline__ float wave_max_nn(float v)
{
    v = dpp_fmax<0x111>(v);   // row_shr:1
    v = dpp_fmax<0x112>(v);   // row_shr:2
    v = dpp_fmax<0x114>(v);   // row_shr:4
    v = dpp_fmax<0x118>(v);   // row_shr:8  -> lane 15/31/47/63 = row max
    v = dpp_fmax<0x142>(v);   // row_bcast:15 -> lane 31/63 = half max
    v = dpp_fmax<0x143>(v);   // row_bcast:31 -> lane 63 = wave max
    return v;
}

// nrm: fp32, squares rounded individually, sequential sum over c, mirrors np.
// Also zero-initializes the loss accumulator + completion counter (replaces
// hipMemsetAsync launch).
__global__ void k_normalize(const float* __restrict__ D, float* __restrict__ Dn,
                            double* __restrict__ loss_acc, unsigned int* __restrict__ ctr)
{
#pragma clang fp contract(off)
    int n = threadIdx.x;   // one thread per column, 256 threads
    if (n == 0) { loss_acc[0] = 0.0; ctr[0] = 0u; }
    float ss = 0.0f;
    for (int c = 0; c < DIM; c++) {
        float v = D[c * NEMB + n];
        float sq = v * v;
        ss = ss + sq;
    }
    float nrm = fmaxf(sqrtf(ss), 1e-10f);
    for (int c = 0; c < DIM; c++)
        Dn[c * NEMB + n] = D[c * NEMB + n] / nrm;
}

// G = Dn^T Dn: fp32, fused-FMA sequential over k ascending (BLAS sgemm order)
__global__ void k_gram(const float* __restrict__ Dn, float* __restrict__ G)
{
    __shared__ float coli[DIM];
    int i = blockIdx.x, j = threadIdx.x;
    if (j < DIM) coli[j] = Dn[j * NEMB + i];
    __syncthreads();
    float s = 0.0f;
#pragma unroll
    for (int c = 0; c < DIM; c++) s = fmaf(coli[c], Dn[c * NEMB + j], s);
    G[i * NEMB + j] = s;
}

// mu-law quantize+decode, all fp32, numpy op-for-op (no fusion)
__device__ __forceinline__ float quant_decode(float coeff)
{
#pragma clang fp contract(off)
    float c = fminf(fmaxf(coeff, -3.0f), 3.0f) / 3.0f;
    float ac = fabsf(c);
    float sgn = (c > 0.0f) ? 1.0f : ((c < 0.0f) ? -1.0f : 0.0f);
    float l = log1pf(ac * 50.0f);
    float enc = (sgn * l) * INV_MU_F;
    float scaled = (enc + 1.0f) * 7.5f;
    int bin = (int)rintf(scaled);              // round-half-even == np.round
    bin = bin < 0 ? 0 : (bin > 15 ? 15 : bin);
    float t = (float)bin * TWO15_F;
    float zv = t - 1.0f;
    float az = fabsf(zv);
    float sz = (zv > 0.0f) ? 1.0f : ((zv < 0.0f) ? -1.0f : 0.0f);
    float e = expm1f(az / INV_MU_F);
    return (sz * (e / 50.0f)) * 3.0f;
}

// TWO signals' OMP (K=4) per call: argmax/residual stay distributed over all
// 64 lanes per signal (4 atoms/lane, same layout as h_bar GEMM output), but
// the wave-uniform Cholesky + triangular solves run ONCE on half-selected
// operands: lanes 0-31 compute signal A's recurrence, lanes 32-63 signal B's.
// Arithmetic sequence per signal is bit-identical to the passing 1-signal
// version: same IEEE div/sqrt, same op order, same first-index tie-break.
//  - divides by L[0][0]==1.0 removed (exact identity): 20 -> 12 per signal
//  - G[Iv[j]][idx] taken from the cached G-row registers via readlane
//    (same stored value, no memory op on the Cholesky critical path)
//  - residual update packed as float2 (v_pk_mul/add, elementwise-exact)
__device__ __forceinline__ void omp_pair(const f2* hbA_in, const f2* hbB_in,
                                         int lane, int hi,
                                         const float* __restrict__ G,
                                         float* __restrict__ xsv,
                                         int* __restrict__ qi, int sA)
{
#pragma clang fp contract(off)
    f2 hbsiA[2] = {hbA_in[0], hbA_in[1]};
    f2 hbsiB[2] = {hbB_in[0], hbB_in[1]};
    f2 hA[2] = {hbsiA[0], hbsiA[1]};
    f2 hB[2] = {hbsiB[0], hbsiB[1]};
    f2 GrA[3][2], GrB[3][2];
    float Lm[4][4];
    int IvA[4], IvB[4];
    float y[4], xs[4];
    int m4A = 0, m4B = 0;
#pragma unroll
    for (int kk = 0; kk < 4; kk++) {
        // ---- per-lane best of own 4 atoms, both signals (independent ILP) ----
        float bvA = -1.0f, bvB = -1.0f;
        int bjA = 0, bjB = 0;
#pragma unroll
        for (int j = 0; j < 4; j++) {
            float vA_ = (m4A & (1 << j)) ? 0.0f : fabsf(hA[j >> 1][j & 1]);
            if (vA_ > bvA) { bvA = vA_; bjA = j; }
            float vB_ = (m4B & (1 << j)) ? 0.0f : fabsf(hB[j >> 1][j & 1]);
            if (vB_ > bvB) { bvB = vB_; bjB = j; }
        }
        // ---- wave max via DPP (value only), two independent chains ----
        float mA = wave_max_nn(bvA);
        float mB = wave_max_nn(bvB);
        float vmaxA = rdlane_f(mA, 63);
        float vmaxB = rdlane_f(mB, 63);
        // ---- first lane holding the max = numpy first-index tie-break ----
        unsigned long long ballA = __ballot(bvA == vmaxA);
        unsigned long long ballB = __ballot(bvB == vmaxB);
        int ownerA = __ffsll((long long)ballA) - 1;
        int ownerB = __ffsll((long long)ballB) - 1;
        int bjAo = __builtin_amdgcn_readlane(bjA, ownerA);
        int bjBo = __builtin_amdgcn_readlane(bjB, ownerB);
        int idxA = 4 * ownerA + bjAo;
        int idxB = 4 * ownerB + bjBo;
        m4A |= (lane == ownerA) ? (1 << bjAo) : 0;
        m4B |= (lane == ownerB) ? (1 << bjBo) : 0;
        IvA[kk] = idxA; IvB[kk] = idxB;
        // ---- original h_bar value at selected atom ----
        float tvA = hbsiA[0][0];
        tvA = (bjA == 1) ? hbsiA[0][1] : tvA;
        tvA = (bjA == 2) ? hbsiA[1][0] : tvA;
        tvA = (bjA == 3) ? hbsiA[1][1] : tvA;
        float tvB = hbsiB[0][0];
        tvB = (bjB == 1) ? hbsiB[0][1] : tvB;
        tvB = (bjB == 2) ? hbsiB[1][0] : tvB;
        tvB = (bjB == 3) ? hbsiB[1][1] : tvB;
        float hselA = rdlane_f(tvA, ownerA);
        float hselB = rdlane_f(tvB, ownerB);
        float hsel = hi ? hselB : hselA;
        // ---- cache G rows for this atom (float4/lane, coalesced, L2-hot) ----
        if (kk < 3) {
            const float4 ga = *(const float4*)(G + ((size_t)idxA << 8) + 4 * lane);
            const float4 gb = *(const float4*)(G + ((size_t)idxB << 8) + 4 * lane);
            GrA[kk][0].x = ga.x; GrA[kk][0].y = ga.y;
            GrA[kk][1].x = ga.z; GrA[kk][1].y = ga.w;
            GrB[kk][0].x = gb.x; GrB[kk][0].y = gb.y;
            GrB[kk][1].x = gb.z; GrB[kk][1].y = gb.w;
        }
        // ---- Cholesky row update (halves: A on lanes 0-31, B on 32-63) ----
        if (kk > 0) {
            float Gs[3], w[3];
#pragma unroll
            for (int j = 0; j < 3; j++)
                if (j < kk) {
                    // G[Iv[j]][idx] == element bj_o of cached row j at lane owner
                    float eA = GrA[j][0][0];
                    eA = (bjAo == 1) ? GrA[j][0][1] : eA;
                    eA = (bjAo == 2) ? GrA[j][1][0] : eA;
                    eA = (bjAo == 3) ? GrA[j][1][1] : eA;
                    float eB = GrB[j][0][0];
                    eB = (bjBo == 1) ? GrB[j][0][1] : eB;
                    eB = (bjBo == 2) ? GrB[j][1][0] : eB;
                    eB = (bjBo == 3) ? GrB[j][1][1] : eB;
                    float gA = rdlane_f(eA, ownerA);
                    float gB = rdlane_f(eB, ownerB);
                    Gs[j] = hi ? gB : gA;
                }
#pragma unroll
            for (int r = 0; r < 3; r++) {
                if (r < kk) {
                    float acc = 0.0f;
#pragma unroll
                    for (int cc = 0; cc < 3; cc++)
                        if (cc < r) { float p = Lm[r][cc] * w[cc]; acc = acc + p; }
                    float t2 = Gs[r] - acc;
                    w[r] = (r == 0) ? t2 : t2 / Lm[r][r];   // L[0][0]==1: exact
                }
            }
            float ssum = 0.0f;
#pragma unroll
            for (int j = 0; j < 3; j++)
                if (j < kk) { float p = w[j] * w[j]; ssum = ssum + p; }
            float om = 1.0f - ssum;
            float wc = sqrtf(fmaxf(om, 1e-12f));
#pragma unroll
            for (int cc = 0; cc < 3; cc++)
                if (cc < kk) Lm[kk][cc] = w[cc];
            Lm[kk][kk] = wc;
        } else {
            Lm[0][0] = 1.0f;
        }
        // ---- forward solve, incremental: only row kk is new ----
        {
            float acc = 0.0f;
#pragma unroll
            for (int cc = 0; cc < 3; cc++)
                if (cc < kk) { float p = Lm[kk][cc] * y[cc]; acc = acc + p; }
            float t2 = hsel - acc;
            y[kk] = (kk == 0) ? t2 : t2 / Lm[kk][kk];
        }
        // ---- backward solve L^T x = y (full, sum ascending c>r) ----
#pragma unroll
        for (int r = 3; r >= 0; r--) {
            if (r <= kk) {
                float acc = 0.0f;
#pragma unroll
                for (int cc = 0; cc < 4; cc++)
                    if (cc > r && cc <= kk) { float p = Lm[cc][r] * xs[cc]; acc = acc + p; }
                float t2 = y[r] - acc;
                xs[r] = (r == 0) ? t2 : t2 / Lm[r][r];      // L[0][0]==1: exact
            }
        }
        // ---- residual: h = h_bar - einsum(x, G[I]) (mul+add, k ascending) ----
        if (kk < 3) {
            float xsA[4], xsB[4];
#pragma unroll
            for (int j = 0; j < 4; j++)
                if (j <= kk) {
                    xsA[j] = rdlane_f(xs[j], 0);
                    xsB[j] = rdlane_f(xs[j], 32);
                }
#pragma unroll
            for (int jp = 0; jp < 2; jp++) {
                f2 bsA = {0.0f, 0.0f};
                f2 bsB = {0.0f, 0.0f};
#pragma unroll
                for (int jj = 0; jj < 3; jj++)
                    if (jj <= kk) {
                        f2 xa = {xsA[jj], xsA[jj]};
                        f2 xb = {xsB[jj], xsB[jj]};
                        f2 pA = xa * GrA[jj][jp];
                        bsA = bsA + pA;
                        f2 pB = xb * GrB[jj][jp];
                        bsB = bsB + pB;
                    }
                hA[jp] = hbsiA[jp] - bsA;
                hB[jp] = hbsiB[jp] - bsB;
            }
        }
    }
    // lane 0 writes signal A, lane 32 writes signal B
    if ((lane & 31) == 0) {
        int s = sA + hi;
#pragma unroll
        for (int j = 0; j < 4; j++) {
            xsv[j * SIGS + s] = xs[j];   // raw coeff; quantized later in parallel
            qi[j * SIGS + s] = hi ? IvB[j] : IvA[j];
        }
    }
}

__launch_bounds__(THREADS, 4)
__global__ void k_omp(const float* __restrict__ z,
                      const float* __restrict__ Dn_g,
                      const float* __restrict__ G,
                      double* __restrict__ loss_acc,
                      unsigned int* __restrict__ ctr,
                      float* __restrict__ zq,
                      float* __restrict__ loss_out)
{
    extern __shared__ char smem[];
    float* sig = (float*)(smem + LB_SIG);
    float* xsv = (float*)(smem + LB_XS);
    int* qi = (int*)(smem + LB_QI);
    double* red = (double*)(smem + LB_RED);

    int tid = threadIdx.x;
    int lane = tid & 63;
    int hi = lane >> 5;
    int wid = tid >> 6;

    long sbase = (long)blockIdx.x * SIGS;   // 128 consecutive pixels, one batch b
    int b = (int)(sbase >> 12);
    int pl0 = (int)(sbase & 4095);
    const float* zb = z + ((size_t)b << 18) + pl0;
    // stage z_e -> sig[c][w], coalesced along w
    {
        int w = tid & (SIGS - 1);
        int g = tid >> 7;
#pragma unroll
        for (int i = 0; i < 16; i++) {
            int c = g * 16 + i;
            sig[c * SIGS + w] = zb[(size_t)c * 4096 + w];
        }
    }
    __syncthreads();

    // each wave: 16 signals in 2 groups of 8; h_bar = X^T Dn, fp32 fused-FMA
    // sequential over c ascending, packed as float2 -> v_pk_fma_f32
    // (elementwise-identical fma chains). Dn read from global (L1/L2-hot).
    for (int g2 = 0; g2 < 2; g2++) {
        int s0 = wid * 16 + g2 * 8;
        f2 hb[8][2];
#pragma unroll
        for (int a = 0; a < 8; a++) {
            hb[a][0] = (f2){0.0f, 0.0f};
            hb[a][1] = (f2){0.0f, 0.0f};
        }
#pragma unroll 8
        for (int c = 0; c < DIM; c++) {
            float4 sva = *(const float4*)(sig + c * SIGS + s0);
            float4 svb = *(const float4*)(sig + c * SIGS + s0 + 4);
            float s8[8] = {sva.x, sva.y, sva.z, sva.w, svb.x, svb.y, svb.z, svb.w};
            float4 dv = *(const float4*)(Dn_g + c * NEMB + 4 * lane);
            f2 d0; d0.x = dv.x; d0.y = dv.y;
            f2 d1; d1.x = dv.z; d1.y = dv.w;
#pragma unroll
            for (int a = 0; a < 8; a++) {
                f2 sa = {s8[a], s8[a]};
                hb[a][0] = __builtin_elementwise_fma(sa, d0, hb[a][0]);
                hb[a][1] = __builtin_elementwise_fma(sa, d1, hb[a][1]);
            }
        }
#pragma unroll
        for (int p = 0; p < 4; p++)
            omp_pair(hb[2 * p], hb[2 * p + 1], lane, hi, G, xsv, qi, s0 + 2 * p);
    }
    __syncthreads();

    // thread-parallel mu-law quantize of all 512 coeffs
    {
        int jq = tid >> 7;
        int wq = tid & (SIGS - 1);
        xsv[jq * SIGS + wq] = quant_decode(xsv[jq * SIGS + wq]);
    }
    __syncthreads();

    // store phase: recon (einsum order: mul+add, k ascending, no fma),
    // z_q = z_e + (recon - z_e), loss accumulated in f64
    double lsum = 0.0;
    float* zqb = zq + ((size_t)b << 18) + pl0;
    {
#pragma clang fp contract(off)
        int w = tid & (SIGS - 1);
        int g = tid >> 7;
        float q0 = xsv[0 * SIGS + w], q1 = xsv[1 * SIGS + w];
        float q2 = xsv[2 * SIGS + w], q3 = xsv[3 * SIGS + w];
        int i0 = qi[0 * SIGS + w], i1 = qi[1 * SIGS + w];
        int i2 = qi[2 * SIGS + w], i3 = qi[3 * SIGS + w];
#pragma unroll
        for (int ci = 0; ci < 16; ci++) {
            int c = g * 16 + ci;
            const float* dr = Dn_g + c * NEMB;
            float p0 = q0 * dr[i0];
            float p1 = q1 * dr[i1];
            float p2 = q2 * dr[i2];
            float p3 = q3 * dr[i3];
            float r = p0 + p1;
            r = r + p2;
            r = r + p3;
            float zev = sig[c * SIGS + w];
            float d = r - zev;
            float zqv = zev + d;           // z_q = z_e + (recon - z_e)
            lsum += (double)d * (double)d;
            zqb[(size_t)c * 4096 + w] = zqv;
        }
    }
#pragma unroll
    for (int off = 32; off > 0; off >>= 1) lsum += __shfl_xor(lsum, off);
    if (lane == 0) red[wid] = lsum;
    __syncthreads();
    if (tid == 0) {
        double t = 0.0;
#pragma unroll
        for (int i = 0; i < 8; i++) t += red[i];
        atomicAdd(loss_acc, t);
        __threadfence();
        unsigned int done = atomicAdd(ctr, 1u);
        if (done == GRID - 1) {
            // last block: fold the k_final launch in here
            double m = atomicAdd(loss_acc, 0.0) / 8388608.0;
            loss_out[0] = (float)(m + 0.25 * m);
        }
    }
}

extern "C" void kernel_launch(void* const* d_in, const int* in_sizes, int n_in,
                              void* d_out, int out_size, void* d_ws, size_t ws_size,
                              hipStream_t stream)
{
    const float* z = (const float*)d_in[0];
    const float* D = (const float*)d_in[1];
    float* out = (float*)d_out;
    char* ws = (char*)d_ws;
    double* loss_acc = (double*)ws;              // 8 B
    unsigned int* ctr = (unsigned int*)(ws + 8); // 4 B, re-zeroed each replay
    float* Dn = (float*)(ws + 256);              // 64x256 f32
    float* G = (float*)(ws + 256 + 65536);       // 256x256 f32

    k_normalize<<<1, NEMB, 0, stream>>>(D, Dn, loss_acc, ctr);
    k_gram<<<NEMB, NEMB, 0, stream>>>(Dn, G);
    hipFuncSetAttribute(reinterpret_cast<const void*>(k_omp),
                        hipFuncAttributeMaxDynamicSharedMemorySize, LDS_BYTES);
    k_omp<<<GRID, THREADS, LDS_BYTES, stream>>>(z, Dn, G, loss_acc, ctr, out, out + 8388608);
    (void)in_sizes; (void)n_in; (void)out_size; (void)ws_size;
}